// Round 12
// baseline (192.252 us; speedup 1.0000x reference)
//
#include <hip/hip_runtime.h>

#define VOCAB 1024
#define HIDDEN 64
#define N_POS 131072            // 32*64*64 positions
#define Q_ELEMS 8388608
#define BPOS 512                // positions per block
#define NBLK 256                // 1 block per CU

// d_out layout (floats): [0]=loss, [1..8388608]=quantized_st (NCHW),
// [8388609]=perplexity, [8388610..]=one_hot [131072,1024]
#define OUT_Q_OFF 1
#define OUT_PPL_OFF 8388609
#define OUT_OH_OFF 8388610ULL

typedef __attribute__((ext_vector_type(8))) short short8v;  // bf16x8 MFMA frag
typedef __attribute__((ext_vector_type(4))) float f32x4;

__device__ __forceinline__ short bf16r(float f) {
    union { float f; unsigned u; } v; v.f = f;
    unsigned r = v.u + 0x7FFFu + ((v.u >> 16) & 1u);   // RNE
    return (short)(r >> 16);
}

// 256 blocks x 512 threads, 1 block/CU. Runs AFTER the one_hot memset, so the
// single data-dependent 1.0 per row can be scattered directly. All 8 waves
// compute: stage full bf16 codebook once (128 KB LDS), each wave owns 64
// positions, MFMA argmax with idx-in-mantissa, loss from the max, q gather.
__global__ __launch_bounds__(512, 1) void vq_compute(
    const float* __restrict__ in, const float* __restrict__ cb,
    float* __restrict__ out, float* __restrict__ ws_loss,
    unsigned* __restrict__ counts)
{
    __shared__ short cbs[VOCAB * HIDDEN];     // 128 KB, XOR-swizzled bf16
    __shared__ float bsqs[VOCAB];             // 4 KB, -0.5*|c|^2
    __shared__ unsigned hist[VOCAB];          // 4 KB

    const int tid  = threadIdx.x;
    const int wid  = tid >> 6;
    const int lane = tid & 63;
    const int bid  = blockIdx.x;
    const int base = bid * BPOS;
    const int b    = base >> 12;       // NCHW batch index, uniform per block
    const int hw0  = base & 4095;

    for (int k = tid; k < VOCAB; k += 512) hist[k] = 0u;

    // ---- stage the whole codebook as swizzled bf16 (all 8 waves) ----
    {
        const float4* src = (const float4*)cb;
#pragma unroll 4
        for (int it = 0; it < 32; ++it) {
            int i = tid + it * 512;
            int row = i >> 4, c4 = i & 15;
            float4 v = src[i];
            float ss = v.x * v.x + v.y * v.y + v.z * v.z + v.w * v.w;
            ss += __shfl_xor(ss, 1);
            ss += __shfl_xor(ss, 2);
            ss += __shfl_xor(ss, 4);
            ss += __shfl_xor(ss, 8);
            unsigned lo = ((unsigned)(unsigned short)bf16r(v.x))
                        | ((unsigned)(unsigned short)bf16r(v.y) << 16);
            unsigned hi = ((unsigned)(unsigned short)bf16r(v.z))
                        | ((unsigned)(unsigned short)bf16r(v.w) << 16);
            int boff = row * 128 + ((c4 * 8) ^ ((row & 7) << 4));
            *(uint2*)((char*)cbs + boff) = make_uint2(lo, hi);
            if (c4 == 0) bsqs[row] = -0.5f * ss;
        }
    }

    // ---- x fragments + per-lane |x|^2 (loads overlap staging) ----
    // wave wid owns positions [wid*64, wid*64+64); B-frag col = bt*16 + l15
    const int l15 = lane & 15, kg = lane >> 4;
    const int kg4 = kg << 2, kgb = kg << 4;
    short8v xf[4][2];
    float xsq[4];
#pragma unroll
    for (int bt = 0; bt < 4; ++bt) {
        xsq[bt] = 0.f;
#pragma unroll
        for (int kh = 0; kh < 2; ++kh) {
            const float* xp = in + (size_t)b * 262144
                            + (size_t)(kh * 32 + kg * 8) * 4096
                            + hw0 + wid * 64 + bt * 16 + l15;
            short8v v;
#pragma unroll
            for (int e = 0; e < 8; ++e) {
                float x = xp[(size_t)e * 4096];
                xsq[bt] = fmaf(x, x, xsq[bt]);
                v[e] = bf16r(x);
            }
            xf[bt][kh] = v;
        }
    }

    __syncthreads();     // staging complete

    // ---- MFMA argmax over all 1024 codes ----
    float rm[4];
#pragma unroll
    for (int bt = 0; bt < 4; ++bt) rm[bt] = -3.4e38f;

    for (int ct = 0; ct < 64; ++ct) {
        const int rbase = ct * 16 + l15;               // A-frag row = code
        const char* arow = (const char*)cbs + rbase * 128;
        const int sw = (rbase & 7) << 4;
        short8v a0 = *(const short8v*)(arow + (kgb ^ sw));          // k 0..31
        short8v a1 = *(const short8v*)(arow + ((64 + kgb) ^ sw));   // k 32..63
        f32x4 bsq4 = *(const f32x4*)&bsqs[ct * 16 + kg4];
        const unsigned jb = (unsigned)(ct * 16 + kg4);
#pragma unroll
        for (int bt = 0; bt < 4; ++bt) {
            f32x4 acc = bsq4;
            acc = __builtin_amdgcn_mfma_f32_16x16x32_bf16(a0, xf[bt][0], acc, 0, 0, 0);
            acc = __builtin_amdgcn_mfma_f32_16x16x32_bf16(a1, xf[bt][1], acc, 0, 0, 0);
#pragma unroll
            for (int r = 0; r < 4; ++r) {
                unsigned pj = (__float_as_uint(acc[r]) & 0xFFFFFC00u) | (jb + r);
                rm[bt] = fmaxf(rm[bt], __uint_as_float(pj));
            }
        }
    }

    // ---- full butterfly over kg: every lane owns its column's max ----
    float mred[4], xred[4];
#pragma unroll
    for (int bt = 0; bt < 4; ++bt) {
        float m = rm[bt], xs = xsq[bt];
        m  = fmaxf(m, __shfl_xor(m, 16));
        xs += __shfl_xor(xs, 16);
        m  = fmaxf(m, __shfl_xor(m, 32));
        xs += __shfl_xor(xs, 32);
        mred[bt] = m; xred[bt] = xs;
    }
    const int sel = kg;        // lane L owns col L: bt == kg (static selects)
    const float m  = sel == 0 ? mred[0] : sel == 1 ? mred[1]
                   : sel == 2 ? mred[2] : mred[3];
    const float xs = sel == 0 ? xred[0] : sel == 1 ? xred[1]
                   : sel == 2 ? xred[2] : xred[3];
    const unsigned mu = __float_as_uint(m);
    const int   jf   = (int)(mu & 1023u);
    const float mval = __uint_as_float(mu & 0xFFFFFC00u);
    float lsum = xs - 2.f * mval;    // |x-c|^2 = |x|^2 - 2(x.c - 0.5|c|^2)

    const int p = wid * 64 + lane;   // block-relative position

    // ---- the 1.0 scatter (zeros already committed by memset) ----
    out[OUT_OH_OFF + (size_t)(base + p) * VOCAB + jf] = 1.0f;

    // ---- q write: gather fp32 code row, store NCHW (quantized_st == q) ----
    {
        const float4* cr4 = (const float4*)(cb + (size_t)jf * HIDDEN);
        float* qp = out + OUT_Q_OFF + (size_t)b * 262144 + hw0 + p;
#pragma unroll
        for (int c4 = 0; c4 < 16; ++c4) {
            float4 v = cr4[c4];
            __builtin_nontemporal_store(v.x, &qp[(size_t)(4 * c4 + 0) * 4096]);
            __builtin_nontemporal_store(v.y, &qp[(size_t)(4 * c4 + 1) * 4096]);
            __builtin_nontemporal_store(v.z, &qp[(size_t)(4 * c4 + 2) * 4096]);
            __builtin_nontemporal_store(v.w, &qp[(size_t)(4 * c4 + 3) * 4096]);
        }
    }

    // ---- histogram + loss ----
    atomicAdd(&hist[jf], 1u);
    __syncthreads();
    for (int k = tid; k < VOCAB; k += 512) {
        unsigned h = hist[k];
        if (h) atomicAdd(&counts[k], h);
    }
#pragma unroll
    for (int off = 32; off; off >>= 1) lsum += __shfl_down(lsum, off);
    if (lane == 0) atomicAdd(&ws_loss[bid & 63], lsum);
}

__global__ void vq_finalize(const unsigned* __restrict__ counts,
                            const float* __restrict__ ws_loss,
                            float* __restrict__ out)
{
    __shared__ double red[4];
    const int tid = threadIdx.x;
    double s = 0.0;
    for (int k = tid; k < VOCAB; k += 256) {
        double p = (double)counts[k] / (double)N_POS;
        s += -p * log(p + 1e-10);
    }
#pragma unroll
    for (int off = 32; off; off >>= 1) s += __shfl_down(s, off);
    if ((tid & 63) == 0) red[tid >> 6] = s;
    __syncthreads();
    if (tid == 0) {
        double e = red[0] + red[1] + red[2] + red[3];
        out[OUT_PPL_OFF] = (float)exp(e);
        float l = 0.f;
#pragma unroll
        for (int k = 0; k < 64; ++k) l += ws_loss[k];
        out[0] = l * 1.25f / (float)Q_ELEMS;
    }
}

extern "C" void kernel_launch(void* const* d_in, const int* in_sizes, int n_in,
                              void* d_out, int out_size, void* d_ws, size_t ws_size,
                              hipStream_t stream) {
    const float* in = (const float*)d_in[0];
    const float* cb = (const float*)d_in[1];
    float* out = (float*)d_out;

    float*    ws_loss = (float*)d_ws;                 // 64 f32 slots
    unsigned* counts  = (unsigned*)d_ws + 64;         // 1024 u32

    // zero one_hot at the runtime fill's proven 6.6 TB/s, then fast compute
    (void)hipMemsetAsync(out + OUT_OH_OFF, 0,
                         (size_t)N_POS * VOCAB * sizeof(float), stream);
    (void)hipMemsetAsync(d_ws, 0, 4352, stream);      // loss slots + counts
    vq_compute<<<NBLK, 512, 0, stream>>>(in, cb, out, ws_loss, counts);
    vq_finalize<<<1, 256, 0, stream>>>(counts, ws_loss, out);
}

// Round 13
// 188.455 us; speedup vs baseline: 1.0201x; 1.0201x over previous
//
#include <hip/hip_runtime.h>

#define VOCAB 1024
#define HIDDEN 64
#define N_POS 131072            // 32*64*64 positions
#define Q_ELEMS 8388608
#define BPOS 512                // positions per block
#define NBLK 256                // 1 block per CU

// d_out layout (floats): [0]=loss, [1..8388608]=quantized_st (NCHW),
// [8388609]=perplexity, [8388610..]=one_hot [131072,1024]
#define OUT_Q_OFF 1
#define OUT_PPL_OFF 8388609
#define OUT_OH_OFF 8388610ULL

typedef __attribute__((ext_vector_type(8))) short short8v;  // bf16x8 MFMA frag
typedef __attribute__((ext_vector_type(4))) float f32x4;

__device__ __forceinline__ short bf16r(float f) {
    union { float f; unsigned u; } v; v.f = f;
    unsigned r = v.u + 0x7FFFu + ((v.u >> 16) & 1u);   // RNE
    return (short)(r >> 16);
}

// 256 blocks x 1024 threads (16 waves), 1 block/CU.
// Waves 0-7: compute 512 positions (stage-once codebook, MFMA argmax,
//            loss-from-max, q writes), then join the zero stream.
// Waves 8-15: PURE zero-store waves -- 192 plain float4 stores each,
//            started right after staging (no idx dependency).
// The data-dependent 1.0 is scattered after the vmcnt-draining barrier.
__global__ __launch_bounds__(1024, 4) void vq_fused(
    const float* __restrict__ in, const float* __restrict__ cb,
    float* __restrict__ out, float* __restrict__ ws_loss,
    unsigned* __restrict__ counts)
{
    __shared__ short cbs[VOCAB * HIDDEN];     // 128 KB, XOR-swizzled bf16
    __shared__ float bsqs[VOCAB];             // 4 KB, -0.5*|c|^2
    __shared__ unsigned hist[VOCAB];          // 4 KB
    __shared__ int idx_lds[BPOS];             // 2 KB

    const int tid  = threadIdx.x;
    const int wid  = tid >> 6;
    const int lane = tid & 63;
    const int bid  = blockIdx.x;
    const int base = bid * BPOS;
    const int b    = base >> 12;       // NCHW batch index, uniform per block
    const int hw0  = base & 4095;

    float* ohflat = out + OUT_OH_OFF + (size_t)bid * 524288;
    float4* oh4   = (float4*)(ohflat + 2);    // 16B aligned, slots 0..131070

    if (tid < VOCAB) hist[tid] = 0u;

    // ---- stage the whole codebook as swizzled bf16 (all 16 waves) ----
    {
        const float4* src = (const float4*)cb;
#pragma unroll 4
        for (int it = 0; it < 16; ++it) {
            int i = tid + it * 1024;
            int row = i >> 4, c4 = i & 15;
            float4 v = src[i];
            float ss = v.x * v.x + v.y * v.y + v.z * v.z + v.w * v.w;
            ss += __shfl_xor(ss, 1);
            ss += __shfl_xor(ss, 2);
            ss += __shfl_xor(ss, 4);
            ss += __shfl_xor(ss, 8);
            unsigned lo = ((unsigned)(unsigned short)bf16r(v.x))
                        | ((unsigned)(unsigned short)bf16r(v.y) << 16);
            unsigned hi = ((unsigned)(unsigned short)bf16r(v.z))
                        | ((unsigned)(unsigned short)bf16r(v.w) << 16);
            int boff = row * 128 + ((c4 * 8) ^ ((row & 7) << 4));
            *(uint2*)((char*)cbs + boff) = make_uint2(lo, hi);
            if (c4 == 0) bsqs[row] = -0.5f * ss;
        }
    }

    __syncthreads();     // B1: staging complete

    if (wid < 8) {
        // ======================= compute waves =======================
        const int l15 = lane & 15, kg = lane >> 4;
        const int kg4 = kg << 2, kgb = kg << 4;

        // x fragments + per-lane |x|^2; wave owns positions [wid*64, +64)
        short8v xf[4][2];
        float xsq[4];
#pragma unroll
        for (int bt = 0; bt < 4; ++bt) {
            xsq[bt] = 0.f;
#pragma unroll
            for (int kh = 0; kh < 2; ++kh) {
                const float* xp = in + (size_t)b * 262144
                                + (size_t)(kh * 32 + kg * 8) * 4096
                                + hw0 + wid * 64 + bt * 16 + l15;
                short8v v;
#pragma unroll
                for (int e = 0; e < 8; ++e) {
                    float x = xp[(size_t)e * 4096];
                    xsq[bt] = fmaf(x, x, xsq[bt]);
                    v[e] = bf16r(x);
                }
                xf[bt][kh] = v;
            }
        }

        // MFMA argmax over all 1024 codes
        float rm[4];
#pragma unroll
        for (int bt = 0; bt < 4; ++bt) rm[bt] = -3.4e38f;

        for (int ct = 0; ct < 64; ++ct) {
            const int rbase = ct * 16 + l15;               // A-frag row = code
            const char* arow = (const char*)cbs + rbase * 128;
            const int sw = (rbase & 7) << 4;
            short8v a0 = *(const short8v*)(arow + (kgb ^ sw));          // k 0..31
            short8v a1 = *(const short8v*)(arow + ((64 + kgb) ^ sw));   // k 32..63
            f32x4 bsq4 = *(const f32x4*)&bsqs[ct * 16 + kg4];
            const unsigned jb = (unsigned)(ct * 16 + kg4);
#pragma unroll
            for (int bt = 0; bt < 4; ++bt) {
                f32x4 acc = bsq4;
                acc = __builtin_amdgcn_mfma_f32_16x16x32_bf16(a0, xf[bt][0], acc, 0, 0, 0);
                acc = __builtin_amdgcn_mfma_f32_16x16x32_bf16(a1, xf[bt][1], acc, 0, 0, 0);
#pragma unroll
                for (int r = 0; r < 4; ++r) {
                    unsigned pj = (__float_as_uint(acc[r]) & 0xFFFFFC00u) | (jb + r);
                    rm[bt] = fmaxf(rm[bt], __uint_as_float(pj));
                }
            }
        }

        // full butterfly over kg: every lane owns its column's max
        float mred[4], xred[4];
#pragma unroll
        for (int bt = 0; bt < 4; ++bt) {
            float m = rm[bt], xs = xsq[bt];
            m  = fmaxf(m, __shfl_xor(m, 16));
            xs += __shfl_xor(xs, 16);
            m  = fmaxf(m, __shfl_xor(m, 32));
            xs += __shfl_xor(xs, 32);
            mred[bt] = m; xred[bt] = xs;
        }
        const int sel = kg;        // lane L owns col L: bt == kg
        const float m  = sel == 0 ? mred[0] : sel == 1 ? mred[1]
                       : sel == 2 ? mred[2] : mred[3];
        const float xs = sel == 0 ? xred[0] : sel == 1 ? xred[1]
                       : sel == 2 ? xred[2] : xred[3];
        const unsigned mu = __float_as_uint(m);
        const int   jf   = (int)(mu & 1023u);
        const float mval = __uint_as_float(mu & 0xFFFFFC00u);
        float lsum = xs - 2.f * mval;    // |x-c|^2 = |x|^2 - 2(x.c - 0.5|c|^2)

        const int p = wid * 64 + lane;   // block-relative position (== tid)
        idx_lds[p] = jf;
        atomicAdd(&hist[jf], 1u);

        // q write: gather fp32 code row, store NCHW (quantized_st == q)
        {
            const float4* cr4 = (const float4*)(cb + (size_t)jf * HIDDEN);
            float* qp = out + OUT_Q_OFF + (size_t)b * 262144 + hw0 + p;
#pragma unroll
            for (int c4 = 0; c4 < 16; ++c4) {
                float4 v = cr4[c4];
                __builtin_nontemporal_store(v.x, &qp[(size_t)(4 * c4 + 0) * 4096]);
                __builtin_nontemporal_store(v.y, &qp[(size_t)(4 * c4 + 1) * 4096]);
                __builtin_nontemporal_store(v.z, &qp[(size_t)(4 * c4 + 2) * 4096]);
                __builtin_nontemporal_store(v.w, &qp[(size_t)(4 * c4 + 3) * 4096]);
            }
        }

        // loss reduce (per wave)
#pragma unroll
        for (int off = 32; off; off >>= 1) lsum += __shfl_down(lsum, off);
        if (lane == 0) atomicAdd(&ws_loss[bid & 63], lsum);

        // join the zero stream: slots [98304, 131071)
        const float4 z = make_float4(0.f, 0.f, 0.f, 0.f);
#pragma unroll 4
        for (int k = 0; k < 64; ++k) {
            int s = 98304 + tid + k * 512;
            if (s < 131071) oh4[s] = z;
        }
        if (tid == 0) { ohflat[0] = 0.f; ohflat[1] = 0.f; }               // head
        if (tid == 1) { ohflat[524286] = 0.f; ohflat[524287] = 0.f; }     // tail
    } else {
        // ======================= pure store waves =====================
        // slots [0, 98304): 512 threads x 192 slots, plain float4 stores
        const int w = tid - 512;             // 0..511
        const float4 z = make_float4(0.f, 0.f, 0.f, 0.f);
#pragma unroll 8
        for (int k = 0; k < 192; ++k)
            oh4[w + k * 512] = z;
    }

    __syncthreads();     // B2: drains vmcnt(0) on every wave -> zeros committed

    if (tid < BPOS) {
        // scatter the data-dependent 1.0 (zeros already committed)
        out[OUT_OH_OFF + (size_t)(base + tid) * VOCAB + idx_lds[tid]] = 1.0f;
    }
    // flush histogram
    if (tid < VOCAB) {
        unsigned h = hist[tid];
        if (h) atomicAdd(&counts[tid], h);
    }
}

__global__ void vq_finalize(const unsigned* __restrict__ counts,
                            const float* __restrict__ ws_loss,
                            float* __restrict__ out)
{
    __shared__ double red[4];
    const int tid = threadIdx.x;
    double s = 0.0;
    for (int k = tid; k < VOCAB; k += 256) {
        double p = (double)counts[k] / (double)N_POS;
        s += -p * log(p + 1e-10);
    }
#pragma unroll
    for (int off = 32; off; off >>= 1) s += __shfl_down(s, off);
    if ((tid & 63) == 0) red[tid >> 6] = s;
    __syncthreads();
    if (tid == 0) {
        double e = red[0] + red[1] + red[2] + red[3];
        out[OUT_PPL_OFF] = (float)exp(e);
        float l = 0.f;
#pragma unroll
        for (int k = 0; k < 64; ++k) l += ws_loss[k];
        out[0] = l * 1.25f / (float)Q_ELEMS;
    }
}

extern "C" void kernel_launch(void* const* d_in, const int* in_sizes, int n_in,
                              void* d_out, int out_size, void* d_ws, size_t ws_size,
                              hipStream_t stream) {
    const float* in = (const float*)d_in[0];
    const float* cb = (const float*)d_in[1];
    float* out = (float*)d_out;

    float*    ws_loss = (float*)d_ws;                 // 64 f32 slots
    unsigned* counts  = (unsigned*)d_ws + 64;         // 1024 u32

    (void)hipMemsetAsync(d_ws, 0, 4352, stream);      // zero loss slots + counts
    vq_fused<<<NBLK, 1024, 0, stream>>>(in, cb, out, ws_loss, counts);
    vq_finalize<<<1, 256, 0, stream>>>(counts, ws_loss, out);
}